// Round 1
// baseline (434.584 us; speedup 1.0000x reference)
//
#include <hip/hip_runtime.h>

#define F 128     // F_IN == H == 128
#define COUT 40
#define TR 64     // row tile for gemm+reduce

// ---------------- zero deg + s ----------------
__global__ void k_zero(int* __restrict__ deg, float* __restrict__ s, int n) {
  int i = blockIdx.x * blockDim.x + threadIdx.x;
  int stride = gridDim.x * blockDim.x;
  for (; i < n; i += stride) deg[i] = 0;
  if (blockIdx.x == 0 && threadIdx.x < F) s[threadIdx.x] = 0.f;
}

// ---------------- degree histogram over row ----------------
__global__ void k_hist(const int* __restrict__ row, int E, int* __restrict__ deg) {
  int e = blockIdx.x * blockDim.x + threadIdx.x;
  if (e < E) atomicAdd(&deg[row[e]], 1);
}

// ---------------- scan stage A: per-256-chunk sums ----------------
__global__ void k_scan_a(const int* __restrict__ deg, int N, int* __restrict__ bsum) {
  __shared__ int sm[256];
  int t = threadIdx.x;
  int i = blockIdx.x * 256 + t;
  sm[t] = (i < N) ? deg[i] : 0;
  __syncthreads();
  for (int off = 128; off > 0; off >>= 1) {
    if (t < off) sm[t] += sm[t + off];
    __syncthreads();
  }
  if (t == 0) bsum[blockIdx.x] = sm[0];
}

// ---------------- scan stage B: exclusive scan of block sums (<=512) ----------------
__global__ void k_scan_b(const int* __restrict__ bsum, int nb, int* __restrict__ bpre) {
  __shared__ int sm[512];
  int t = threadIdx.x;  // 512 threads
  int v = (t < nb) ? bsum[t] : 0;
  sm[t] = v;
  __syncthreads();
  for (int off = 1; off < 512; off <<= 1) {
    int x = sm[t];
    int y = (t >= off) ? sm[t - off] : 0;
    __syncthreads();
    sm[t] = x + y;
    __syncthreads();
  }
  if (t < nb) bpre[t] = sm[t] - v;  // exclusive
}

// ---------------- scan stage C: row_ptr, dis, c-init; deg -> fill=0 ----------------
__global__ void k_scan_c(int* __restrict__ deg, int N, int E,
                         const int* __restrict__ bpre,
                         int* __restrict__ row_ptr,
                         float* __restrict__ dis, float* __restrict__ cvec) {
  __shared__ int sm[256];
  int t = threadIdx.x;
  int i = blockIdx.x * 256 + t;
  int d = (i < N) ? deg[i] : 0;
  sm[t] = d;
  __syncthreads();
  for (int off = 1; off < 256; off <<= 1) {
    int x = sm[t];
    int y = (t >= off) ? sm[t - off] : 0;
    __syncthreads();
    sm[t] = x + y;
    __syncthreads();
  }
  if (i < N) {
    row_ptr[i] = bpre[blockIdx.x] + sm[t] - d;  // exclusive prefix
    float r = rsqrtf(1.0f + (float)d);
    dis[i] = r;
    cvec[i] = r * r;     // self-loop weight contribution to column sums
    deg[i] = 0;          // reuse as fill counter
  }
  if (i == 0) row_ptr[N] = E;
}

// ---------------- CSR fill + column-sum accumulation ----------------
__global__ void k_fill(const int* __restrict__ row, const int* __restrict__ col, int E,
                       const float* __restrict__ dis,
                       const int* __restrict__ row_ptr,
                       int* __restrict__ fill,
                       int2* __restrict__ csr,
                       float* __restrict__ cvec) {
  int e = blockIdx.x * blockDim.x + threadIdx.x;
  if (e >= E) return;
  int r = row[e], c = col[e];
  float w = dis[r] * dis[c];
  int slot = row_ptr[r] + atomicAdd(&fill[r], 1);
  csr[slot] = make_int2(c, __float_as_int(w));
  atomicAdd(&cvec[c], w);
}

// ---------------- spmm: one wave per row, z1 = Ahat * X ----------------
__global__ void __launch_bounds__(256) k_spmm(
    const float* __restrict__ X,
    const int* __restrict__ row_ptr,
    const float* __restrict__ dis,
    const int2* __restrict__ csr,
    float* __restrict__ z1, int N) {
  int wave = (blockIdx.x * blockDim.x + threadIdx.x) >> 6;
  int lane = threadIdx.x & 63;
  if (wave >= N) return;
  int rowi = wave;
  float sw = dis[rowi];
  sw *= sw;
  const float2* xr = (const float2*)(X + (long)rowi * F);
  float2 acc = xr[lane];
  acc.x *= sw; acc.y *= sw;
  int e0 = row_ptr[rowi], e1 = row_ptr[rowi + 1];
  int e = e0;
  for (; e + 4 <= e1; e += 4) {
    int2 a0 = csr[e], a1 = csr[e + 1], a2 = csr[e + 2], a3 = csr[e + 3];
    float2 x0 = ((const float2*)(X + (long)a0.x * F))[lane];
    float2 x1 = ((const float2*)(X + (long)a1.x * F))[lane];
    float2 x2 = ((const float2*)(X + (long)a2.x * F))[lane];
    float2 x3 = ((const float2*)(X + (long)a3.x * F))[lane];
    float w0 = __int_as_float(a0.y), w1 = __int_as_float(a1.y);
    float w2 = __int_as_float(a2.y), w3 = __int_as_float(a3.y);
    acc.x += w0 * x0.x + w1 * x1.x + w2 * x2.x + w3 * x3.x;
    acc.y += w0 * x0.y + w1 * x1.y + w2 * x2.y + w3 * x3.y;
  }
  for (; e < e1; ++e) {
    int2 a = csr[e];
    float2 xv = ((const float2*)(X + (long)a.x * F))[lane];
    float w = __int_as_float(a.y);
    acc.x += w * xv.x;
    acc.y += w * xv.y;
  }
  ((float2*)(z1 + (long)rowi * F))[lane] = acc;
}

// ---------------- fused GEMM (z1@W1+b1), relu, weighted column reduction ----------------
__global__ void __launch_bounds__(256) k_gemm_red(
    const float* __restrict__ z1,
    const float* __restrict__ W1,
    const float* __restrict__ b1,
    const float* __restrict__ cvec,
    float* __restrict__ s, int N) {
  __shared__ float zt[TR][F];      // 32 KB
  __shared__ float wsl[16][F];     // 8 KB
  __shared__ float sred[16][F];    // 8 KB
  int t = threadIdx.x;
  int g0 = blockIdx.x * TR;

  // stage z1 tile (zeros past N)
  for (int it = 0; it < 8; ++it) {
    int idx = (it * 256 + t) * 4;
    int r = idx >> 7;
    int c = idx & 127;
    int g = g0 + r;
    float4 v = make_float4(0.f, 0.f, 0.f, 0.f);
    if (g < N) v = *(const float4*)(z1 + (long)g * F + c);
    *(float4*)(&zt[r][c]) = v;
  }

  int tr = t >> 4, tc = t & 15;    // 16x16 thread grid: 4 rows x 8 cols each
  float acc[4][8] = {};

  for (int kb = 0; kb < F; kb += 16) {
    __syncthreads();
    for (int it = 0; it < 2; ++it) {
      int idx = (it * 256 + t) * 4;
      int kk = idx >> 7;
      int c = idx & 127;
      *(float4*)(&wsl[kk][c]) = *(const float4*)(W1 + (long)(kb + kk) * F + c);
    }
    __syncthreads();
#pragma unroll
    for (int kk = 0; kk < 16; ++kk) {
      float a0 = zt[4 * tr + 0][kb + kk];
      float a1 = zt[4 * tr + 1][kb + kk];
      float a2 = zt[4 * tr + 2][kb + kk];
      float a3 = zt[4 * tr + 3][kb + kk];
      float b[8];
      *(float4*)&b[0] = *(float4*)(&wsl[kk][8 * tc]);
      *(float4*)&b[4] = *(float4*)(&wsl[kk][8 * tc + 4]);
#pragma unroll
      for (int j = 0; j < 8; ++j) {
        acc[0][j] += a0 * b[j];
        acc[1][j] += a1 * b[j];
        acc[2][j] += a2 * b[j];
        acc[3][j] += a3 * b[j];
      }
    }
  }

  // epilogue: relu + c-weighted row reduction
  float sacc[8] = {};
#pragma unroll
  for (int j = 0; j < 4; ++j) {
    int g = g0 + 4 * tr + j;
    float cw = (g < N) ? cvec[g] : 0.f;
#pragma unroll
    for (int q = 0; q < 8; ++q) {
      float h = acc[j][q] + b1[8 * tc + q];
      h = h > 0.f ? h : 0.f;
      sacc[q] += cw * h;
    }
  }
#pragma unroll
  for (int q = 0; q < 8; ++q) sred[tr][8 * tc + q] = sacc[q];
  __syncthreads();
  if (t < F) {
    float v = 0.f;
#pragma unroll
    for (int i = 0; i < 16; ++i) v += sred[i][t];
    atomicAdd(&s[t], v);
  }
}

// ---------------- finalize: out = (s/N)@W2 + b2 ----------------
__global__ void k_out(const float* __restrict__ s, const float* __restrict__ W2,
                      const float* __restrict__ b2, float* __restrict__ out,
                      float invN) {
  int j = threadIdx.x;
  if (j >= COUT) return;
  float acc = b2[j];
  for (int k = 0; k < F; ++k) acc += (s[k] * invN) * W2[k * COUT + j];
  out[j] = acc;
}

extern "C" void kernel_launch(void* const* d_in, const int* in_sizes, int n_in,
                              void* d_out, int out_size, void* d_ws, size_t ws_size,
                              hipStream_t stream) {
  const int* edge = (const int*)d_in[0];
  const float* X  = (const float*)d_in[1];
  const float* W1 = (const float*)d_in[2];
  const float* b1 = (const float*)d_in[3];
  const float* W2 = (const float*)d_in[4];
  const float* b2 = (const float*)d_in[5];
  float* out = (float*)d_out;

  int E = in_sizes[0] / 2;
  int N = in_sizes[1] / F;
  const int* row = edge;
  const int* col = edge + E;

  char* w = (char*)d_ws;
  auto alloc = [&](size_t bytes) {
    char* p = w;
    w += (bytes + 255) & ~(size_t)255;
    return p;
  };
  int*   deg     = (int*)alloc((size_t)N * 4);          // later: fill counters
  int*   row_ptr = (int*)alloc(((size_t)N + 1) * 4);
  float* dis     = (float*)alloc((size_t)N * 4);
  float* cvec    = (float*)alloc((size_t)N * 4);
  float* s       = (float*)alloc(512);
  int*   bsum    = (int*)alloc(512 * 4);
  int*   bpre    = (int*)alloc(512 * 4);
  int2*  csr     = (int2*)alloc((size_t)E * 8);
  float* z1      = (float*)alloc((size_t)N * F * 4);

  int nb = (N + 255) / 256;

  k_zero  <<<nb, 256, 0, stream>>>(deg, s, N);
  k_hist  <<<(E + 255) / 256, 256, 0, stream>>>(row, E, deg);
  k_scan_a<<<nb, 256, 0, stream>>>(deg, N, bsum);
  k_scan_b<<<1, 512, 0, stream>>>(bsum, nb, bpre);
  k_scan_c<<<nb, 256, 0, stream>>>(deg, N, E, bpre, row_ptr, dis, cvec);
  k_fill  <<<(E + 255) / 256, 256, 0, stream>>>(row, col, E, dis, row_ptr, deg, csr, cvec);
  k_spmm  <<<(N + 3) / 4, 256, 0, stream>>>(X, row_ptr, dis, csr, z1, N);
  k_gemm_red<<<(N + TR - 1) / TR, 256, 0, stream>>>(z1, W1, b1, cvec, s, N);
  k_out   <<<1, 64, 0, stream>>>(s, W2, b2, out, 1.0f / (float)N);
}